// Round 5
// baseline (451.906 us; speedup 1.0000x reference)
//
#include <hip/hip_runtime.h>
#include <hip/hip_bf16.h>
#include <cstdint>
#include <cstddef>

#define N 4096
#define NN ((size_t)N * (size_t)N)

typedef int int4v  __attribute__((ext_vector_type(4)));
typedef int int16v __attribute__((ext_vector_type(16)));

__device__ inline void async16(const void* g, void* lds) {
    __builtin_amdgcn_global_load_lds(
        (const __attribute__((address_space(1))) void*)g,
        (__attribute__((address_space(3))) void*)lds, 16, 0, 0);
}

// full transcendental path — op-for-op the numpy reference (absmax 0.0, rounds 1-4)
__device__ __noinline__ float mod_full(float p_raw, float uu, float o) {
    float p = fminf(fmaxf(p_raw, 1e-10f), 1.0f - 1e-10f);
    float logits = logf(p) - log1pf(-p);
    float noise  = logf(uu) - log1pf(-uu);
    float y = (logits + noise) / 0.2f;
    float soft = 1.0f / (1.0f + expf(-y));
    float hard = rintf(soft);
    return o + hard * (-2.0f * o);
}

// hybrid: hard = (p+u > 1)  [logit(p)+logit(u) > 0 <=> p+u > 1, exact algebra].
// numpy's float32 logit-sum error ~1e-6 maps to |p+u-1| ~ 3e-7; band 1e-5 is 30x safety.
// In-band elements (expected ~300 of 16.7M) take the proven transcendental path.
__device__ inline float mod_elem(float p_raw, float uu, float o) {
    float p = fmaxf(p_raw, 1e-10f);
    float s = p + uu;
    if (__builtin_expect(fabsf(s - 1.0f) < 1e-5f, 0))
        return mod_full(p_raw, uu, o);
    return (s > 1.0f) ? -o : o;   // o + hard*(-2o), exact
}

// ---------------- kernel 1: diagonal mod prepass + zero accumulators ----------------
__global__ void diag_kernel(const float* __restrict__ ori, const float* __restrict__ clp,
                            const float* __restrict__ u, float* __restrict__ diag,
                            double* __restrict__ accs) {
    int j = blockIdx.x * blockDim.x + threadIdx.x;  // 4096 threads
    size_t idx = (size_t)j * N + j;
    diag[j] = mod_elem(clp[idx], u[idx], ori[idx]);
    if (blockIdx.x == 0 && threadIdx.x < 2) accs[threadIdx.x] = 0.0;
}

__device__ inline int pk4(const int* v) {
    return (v[0] & 255) | ((v[1] & 255) << 8) | ((v[2] & 255) << 16) | ((v[3] & 255) << 24);
}
__device__ inline int pk4a(const int* v) {
    int a0 = v[0] < 0 ? -v[0] : v[0], a1 = v[1] < 0 ? -v[1] : v[1];
    int a2 = v[2] < 0 ? -v[2] : v[2], a3 = v[3] < 0 ? -v[3] : v[3];
    return a0 | (a1 << 8) | (a2 << 16) | (a3 << 24);
}

// ---------------- kernel 2: fused mod + A-build over symmetric 64x64 tile pairs ----------------
// Block (bx<=by): mod for tiles (bi,bj) and (bj,bi) (each element once) -> out,
// then A[i][j] = mod[i][j]+mod[j][i]-mod[j][j] as i8 into A, AT, |A|, |A|T for both tiles.
__global__ __launch_bounds__(256) void fused_mod_A(
        const float* __restrict__ ori, const float* __restrict__ clp,
        const float* __restrict__ u, const float* __restrict__ diag,
        float* __restrict__ out,
        signed char* __restrict__ A, signed char* __restrict__ AT,
        signed char* __restrict__ Aa, signed char* __restrict__ ATa) {
    const int bx = blockIdx.x, by = blockIdx.y;
    if (bx > by) return;
    const bool dg = (bx == by);
    const int bi = bx * 64, bj = by * 64;
    __shared__ float mij[64][68];   // stride 68: 16B-aligned rows for float4 LDS stores
    __shared__ float mji[64][68];
    __shared__ float dj_s[64], di_s[64];
    const int t = threadIdx.x;
    const int r = t >> 2;           // 0..63
    const int c16 = (t & 3) << 4;   // 0,16,32,48
    if (t < 64) dj_s[t] = diag[bj + t];
    else if (t < 128) di_s[t - 64] = diag[bi + t - 64];
    {
        const size_t base = (size_t)(bi + r) * N + bj + c16;
        #pragma unroll
        for (int q = 0; q < 4; ++q) {
            const size_t idx = base + q * 4;
            float4 p4 = *(const float4*)&clp[idx];
            float4 u4 = *(const float4*)&u[idx];
            float4 o4 = *(const float4*)&ori[idx];
            float4 m4;
            m4.x = mod_elem(p4.x, u4.x, o4.x);
            m4.y = mod_elem(p4.y, u4.y, o4.y);
            m4.z = mod_elem(p4.z, u4.z, o4.z);
            m4.w = mod_elem(p4.w, u4.w, o4.w);
            *(float4*)&out[idx] = m4;
            *(float4*)&mij[r][c16 + q * 4] = m4;
        }
    }
    if (!dg) {
        const size_t base = (size_t)(bj + r) * N + bi + c16;
        #pragma unroll
        for (int q = 0; q < 4; ++q) {
            const size_t idx = base + q * 4;
            float4 p4 = *(const float4*)&clp[idx];
            float4 u4 = *(const float4*)&u[idx];
            float4 o4 = *(const float4*)&ori[idx];
            float4 m4;
            m4.x = mod_elem(p4.x, u4.x, o4.x);
            m4.y = mod_elem(p4.y, u4.y, o4.y);
            m4.z = mod_elem(p4.z, u4.z, o4.z);
            m4.w = mod_elem(p4.w, u4.w, o4.w);
            *(float4*)&out[idx] = m4;
            *(float4*)&mji[r][c16 + q * 4] = m4;
        }
    }
    __syncthreads();
    float (*Mji)[68] = dg ? mij : mji;
    int aF[16], tF[16], aM[16], tM[16];
    const float djr = dj_s[r], dir = di_s[r];
    #pragma unroll
    for (int k = 0; k < 16; ++k) {
        const int c = c16 + k;
        const float x  = mij[r][c];
        const float xt = mij[c][r];
        const float y  = Mji[r][c];
        const float yt = Mji[c][r];
        aF[k] = (int)(x + yt - dj_s[c]);   // A[bi+r][bj+c]
        tF[k] = (int)(xt + y - djr);       // AT[bj+r][bi+c] = A[bi+c][bj+r]
        if (!dg) {
            aM[k] = (int)(y + xt - di_s[c]);  // A[bj+r][bi+c]
            tM[k] = (int)(yt + x - dir);      // AT[bi+r][bj+c] = A[bj+c][bi+r]
        }
    }
    const size_t oF = (size_t)(bi + r) * N + bj + c16;
    const size_t oM = (size_t)(bj + r) * N + bi + c16;
    *(int4*)&A  [oF] = make_int4(pk4 (aF), pk4 (aF + 4), pk4 (aF + 8), pk4 (aF + 12));
    *(int4*)&Aa [oF] = make_int4(pk4a(aF), pk4a(aF + 4), pk4a(aF + 8), pk4a(aF + 12));
    *(int4*)&AT [oM] = make_int4(pk4 (tF), pk4 (tF + 4), pk4 (tF + 8), pk4 (tF + 12));
    *(int4*)&ATa[oM] = make_int4(pk4a(tF), pk4a(tF + 4), pk4a(tF + 8), pk4a(tF + 12));
    if (!dg) {
        *(int4*)&A  [oM] = make_int4(pk4 (aM), pk4 (aM + 4), pk4 (aM + 8), pk4 (aM + 12));
        *(int4*)&Aa [oM] = make_int4(pk4a(aM), pk4a(aM + 4), pk4a(aM + 8), pk4a(aM + 12));
        *(int4*)&AT [oF] = make_int4(pk4 (tM), pk4 (tM + 4), pk4 (tM + 8), pk4 (tM + 12));
        *(int4*)&ATa[oF] = make_int4(pk4a(tM), pk4a(tM + 4), pk4a(tM + 8), pk4a(tM + 12));
    }
}

// ---------------- kernel 3: i8 GEMM-trace, 32x32x32 MFMA, BK=128, XOR swizzle (round-4, proven) ---
__global__ __launch_bounds__(256) void gemm_trace_i8(const signed char* __restrict__ Ag,
                                                     const signed char* __restrict__ ATg,
                                                     const signed char* __restrict__ Aag,
                                                     const signed char* __restrict__ ATag,
                                                     double* __restrict__ accs) {
    __shared__ int4v As4[1024];   // [0..511]=K 0..63, [512..1023]=K 64..127
    __shared__ int4v Bs4[1024];
    __shared__ int red[4];
    const int z = blockIdx.z;
    const signed char* Asrc = z ? Aag  : Ag;    // M rows   (i-panel)
    const signed char* Bsrc = z ? ATag : ATg;   // MT rows  (k-panel), B[k][n] = MT[n][k]
    const int i0 = blockIdx.y * 128;
    const int k0 = blockIdx.x * 128;
    const int t = threadIdx.x;
    const int lane = t & 63;
    const int wave = t >> 6;
    const int wr = (wave >> 1) * 64;
    const int wc = (wave & 1) * 64;
    const int m32 = lane & 31;
    const int kg  = lane >> 5;
    signed char* Asc = (signed char*)As4;
    signed char* Bsc = (signed char*)Bs4;

    const int r0 = t >> 2;
    const int c0 = (t & 3) ^ ((r0 >> 1) & 3);
    const signed char* gA = Asrc + (size_t)(i0 + r0) * N + c0 * 16;
    const signed char* gB = Bsrc + (size_t)(k0 + r0) * N + c0 * 16;
    const int ldst = t * 16;

    int16v acc[2][2];
    #pragma unroll
    for (int a = 0; a < 2; ++a)
        #pragma unroll
        for (int b = 0; b < 2; ++b)
            acc[a][b] = (int16v)(0);

    for (int kb = 0; kb < N; kb += 128) {
        __syncthreads();
        const signed char* ga = gA + kb;
        const signed char* gb = gB + kb;
        async16(ga,               Asc + ldst);
        async16(ga + 64 * N,      Asc + 4096  + ldst);
        async16(ga + 64,          Asc + 8192  + ldst);
        async16(ga + 64 * N + 64, Asc + 12288 + ldst);
        async16(gb,               Bsc + ldst);
        async16(gb + 64 * N,      Bsc + 4096  + ldst);
        async16(gb + 64,          Bsc + 8192  + ldst);
        async16(gb + 64 * N + 64, Bsc + 12288 + ldst);
        __syncthreads();
        #pragma unroll
        for (int half = 0; half < 2; ++half) {
            const int hb = half * 8192;
            #pragma unroll
            for (int q = 0; q < 2; ++q) {
                int4v af[2], bf[2];
                #pragma unroll
                for (int tr = 0; tr < 2; ++tr) {
                    const int row = wr + tr * 32 + m32;
                    const int slot = (q * 2 + kg) ^ ((row >> 1) & 3);
                    af[tr] = *(const int4v*)(Asc + hb + (row << 6) + (slot << 4));
                }
                #pragma unroll
                for (int tc = 0; tc < 2; ++tc) {
                    const int row = wc + tc * 32 + m32;
                    const int slot = (q * 2 + kg) ^ ((row >> 1) & 3);
                    bf[tc] = *(const int4v*)(Bsc + hb + (row << 6) + (slot << 4));
                }
                #pragma unroll
                for (int tr = 0; tr < 2; ++tr)
                    #pragma unroll
                    for (int tc = 0; tc < 2; ++tc)
                        acc[tr][tc] = __builtin_amdgcn_mfma_i32_32x32x32_i8(
                            af[tr], bf[tc], acc[tr][tc], 0, 0, 0);
            }
        }
    }

    // epilogue: 32x32 C/D layout col=lane&31, row=(reg&3)+8*(reg>>2)+4*(lane>>5) (m74/m101)
    int part = 0;
    const int rbase = 4 * kg;
    #pragma unroll
    for (int tr = 0; tr < 2; ++tr) {
        #pragma unroll
        for (int tc = 0; tc < 2; ++tc) {
            const int ib = i0 + wr + tr * 32;
            const int kk = k0 + wc + tc * 32 + m32;
            #pragma unroll
            for (int reg = 0; reg < 16; ++reg) {
                const int row = (reg & 3) + 8 * (reg >> 2) + rbase;
                part += acc[tr][tc][reg] * (int)Bsrc[(size_t)(ib + row) * N + kk];
            }
        }
    }
    #pragma unroll
    for (int off = 32; off > 0; off >>= 1)
        part += __shfl_down(part, off, 64);
    if (lane == 0) red[wave] = part;
    __syncthreads();
    if (t == 0) {
        int tot = red[0] + red[1] + red[2] + red[3];
        atomicAdd(&accs[z], (double)tot);
    }
}

// ---------------- kernel 4: balance ----------------
__global__ void finalize_kernel(const double* __restrict__ accs, float* __restrict__ out) {
    out[NN] = (float)(0.5 * (1.0 + accs[0] / accs[1]));
}

extern "C" void kernel_launch(void* const* d_in, const int* in_sizes, int n_in,
                              void* d_out, int out_size, void* d_ws, size_t ws_size,
                              hipStream_t stream) {
    const float* ori = (const float*)d_in[0];
    const float* clp = (const float*)d_in[1];
    const float* u   = (const float*)d_in[2];
    float* out = (float*)d_out;
    char* ws = (char*)d_ws;
    signed char* A8   = (signed char*)ws;                    // 16 MiB
    signed char* AT8  = (signed char*)(ws + NN);             // 16 MiB
    signed char* Aa8  = (signed char*)(ws + 2 * NN);         // 16 MiB
    signed char* ATa8 = (signed char*)(ws + 3 * NN);         // 16 MiB
    float*       diag = (float*)(ws + 4 * NN);               // 16 KiB
    double*      accs = (double*)(ws + 4 * NN + 4096 * 4);   // 16 B

    diag_kernel<<<dim3(16), 256, 0, stream>>>(ori, clp, u, diag, accs);
    fused_mod_A<<<dim3(N / 64, N / 64), 256, 0, stream>>>(ori, clp, u, diag, out,
                                                          A8, AT8, Aa8, ATa8);
    gemm_trace_i8<<<dim3(N / 128, N / 128, 2), 256, 0, stream>>>(A8, AT8, Aa8, ATa8, accs);
    finalize_kernel<<<1, 1, 0, stream>>>(accs, out);
}